// Round 1
// baseline (107.603 us; speedup 1.0000x reference)
//
#include <hip/hip_runtime.h>
#include <hip/hip_cooperative_groups.h>

namespace cg = cooperative_groups;

#define K_SOFT 10.0f
#define LOG2E  1.4426950408889634f
#define MARGIN 3.0f      // e^(-10*3) ~ 1e-13 per omitted pixel -> truncation ~1e-7 total
#define CHUNKS 4         // row-chunk blocks per task (phase-1 parallelism)

__device__ __forceinline__ float wave_reduce(float v) {
#pragma unroll
    for (int off = 32; off > 0; off >>= 1)
        v += __shfl_down(v, off, 64);
    return v;
}

struct Box {
    float cx, cy, kca, ksa, wc, hc;  // kca/ksa = k2*cos/sin; wc/hc = k2*w/2, k2*h/2
    int x0, x1, y0, y1;              // clamped template-index AABB (inclusive)
};

__device__ __forceinline__ Box make_box(const float* __restrict__ p, int i,
                                        float k2, float t0, float inv_dt, int P) {
    Box b;
    b.cx = p[i * 5 + 0];
    b.cy = p[i * 5 + 1];
    const float w = p[i * 5 + 2], h = p[i * 5 + 3], a = p[i * 5 + 4];
    const float ca = cosf(a), sa = sinf(a);
    b.kca = k2 * ca;
    b.ksa = k2 * sa;
    b.wc  = k2 * 0.5f * w;
    b.hc  = k2 * 0.5f * h;
    // AABB of the rotated (w+2M) x (h+2M) support rectangle
    const float hw = 0.5f * w + MARGIN, hh = 0.5f * h + MARGIN;
    const float aca = fabsf(ca), asa = fabsf(sa);
    const float ex = hw * aca + hh * asa;
    const float ey = hw * asa + hh * aca;
    b.x0 = max(0,     (int)ceilf ((b.cx - ex - t0) * inv_dt));
    b.x1 = min(P - 1, (int)floorf((b.cx + ex - t0) * inv_dt));
    b.y0 = max(0,     (int)ceilf ((b.cy - ey - t0) * inv_dt));
    b.y1 = min(P - 1, (int)floorf((b.cy + ey - t0) * inv_dt));
    return b;
}

// Per-block partial sum for task (box, which): 0 = area_p, 1 = area_t, 2 = inter.
// Template is an exact arithmetic progression (dt == 1.0), so pixel coordinates
// are computed by FMA instead of loads; k2 is folded into all row constants.
__device__ __forceinline__ float task_partial(
    const float* __restrict__ pred, const float* __restrict__ target,
    const float* __restrict__ tmpl, int P, int box, int which, int gw, int lane) {
    const float k2 = K_SOFT * LOG2E;
    const float t0 = tmpl[0], dt = tmpl[1] - tmpl[0];
    const float inv_dt = 1.0f / dt;
    const int wstride = 4 * CHUNKS;
    float acc = 0.f;

    if (which < 2) {
        const Box A = make_box(which == 0 ? pred : target, box, k2, t0, inv_dt, P);
        const float bx = t0 - A.cx;
        const float xT = dt * A.kca;    // dT/dxx
        const float xD = -dt * A.ksa;   // dD/dxx
        for (int yy = A.y0 + gw; yy <= A.y1; yy += wstride) {
            const float dyv = fmaf((float)yy, dt, t0) - A.cy;
            const float tb = fmaf(bx,  A.kca, dyv * A.ksa);
            const float db = fmaf(bx, -A.ksa, dyv * A.kca);
            float xf = (float)(A.x0 + lane);
            for (int xx = A.x0 + lane; xx <= A.x1; xx += 64, xf += 64.f) {
                const float T = fmaf(xf, xT, tb);
                const float D = fmaf(xf, xD, db);
                const float e1 = exp2f(fabsf(T) - A.wc);
                const float e2 = exp2f(fabsf(D) - A.hc);
                acc += __builtin_amdgcn_rcpf(1.f + e1) *
                       __builtin_amdgcn_rcpf(1.f + e2);
            }
        }
    } else {
        const Box A = make_box(pred,   box, k2, t0, inv_dt, P);
        const Box B = make_box(target, box, k2, t0, inv_dt, P);
        const int x0 = max(A.x0, B.x0), x1 = min(A.x1, B.x1);
        const int y0 = max(A.y0, B.y0), y1 = min(A.y1, B.y1);
        const float bxA = t0 - A.cx, bxB = t0 - B.cx;
        const float xTA = dt * A.kca, xDA = -dt * A.ksa;
        const float xTB = dt * B.kca, xDB = -dt * B.ksa;
        for (int yy = y0 + gw; yy <= y1; yy += wstride) {
            const float yv = fmaf((float)yy, dt, t0);
            const float dyA = yv - A.cy, dyB = yv - B.cy;
            const float tbA = fmaf(bxA,  A.kca, dyA * A.ksa);
            const float dbA = fmaf(bxA, -A.ksa, dyA * A.kca);
            const float tbB = fmaf(bxB,  B.kca, dyB * B.ksa);
            const float dbB = fmaf(bxB, -B.ksa, dyB * B.kca);
            float xf = (float)(x0 + lane);
            for (int xx = x0 + lane; xx <= x1; xx += 64, xf += 64.f) {
                const float TA = fmaf(xf, xTA, tbA);
                const float DA = fmaf(xf, xDA, dbA);
                const float eA1 = exp2f(fabsf(TA) - A.wc);
                const float eA2 = exp2f(fabsf(DA) - A.hc);
                const float kp = __builtin_amdgcn_rcpf(1.f + eA1) *
                                 __builtin_amdgcn_rcpf(1.f + eA2);
                const float TB = fmaf(xf, xTB, tbB);
                const float DB = fmaf(xf, xDB, dbB);
                const float eB1 = exp2f(fabsf(TB) - B.wc);
                const float eB2 = exp2f(fabsf(DB) - B.hc);
                const float kt = __builtin_amdgcn_rcpf(1.f + eB1) *
                                 __builtin_amdgcn_rcpf(1.f + eB2);
                acc = fmaf(kp, kt, acc);
            }
        }
    }
    return acc;
}

// Single cooperative kernel: phase 1 = all partials, grid sync, phase 2 = loss.
// grid = (CHUNKS, n, 3), block = 256. 384 blocks x 4 waves: trivially co-resident.
__global__ __launch_bounds__(256) void pious_fused(
    const float* __restrict__ pred, const float* __restrict__ target,
    const float* __restrict__ tmpl, float* __restrict__ ws,
    float* __restrict__ out, int P, int n) {
    const int lane = threadIdx.x & 63, wid = threadIdx.x >> 6;
    const int gw = blockIdx.x * 4 + wid;

    const float acc = task_partial(pred, target, tmpl, P,
                                   blockIdx.y, blockIdx.z, gw, lane);

    __shared__ float red[4];
    const float r = wave_reduce(acc);
    if (lane == 0) red[wid] = r;
    __syncthreads();
    if (threadIdx.x == 0) {
        const int task = blockIdx.y * 3 + blockIdx.z;
        ws[task * CHUNKS + blockIdx.x] = red[0] + red[1] + red[2] + red[3];
        __threadfence();   // make the partial visible device-wide before the barrier
    }

    cg::this_grid().sync();

    if (blockIdx.x | blockIdx.y | blockIdx.z) return;

    // phase 2: block (0,0,0) folds 3n x CHUNKS partials and computes the loss
    __shared__ float sums[256];
    const int t = threadIdx.x;
    if (t < 3 * n) {
        float s = 0.f;
#pragma unroll
        for (int c = 0; c < CHUNKS; ++c) s += ws[t * CHUNKS + c];
        sums[t] = s;
    }
    __syncthreads();
    float l = 0.f;
    if (t < n) {   // n = 32 <= 64: all loss lanes live in wave 0
        const float ap    = sums[t * 3 + 0];
        const float at    = sums[t * 3 + 1];
        const float inter = sums[t * 3 + 2];
        float p = inter / (ap + at - inter + 1e-6f);
        p = fminf(fmaxf(p, 0.1f), 1.0f);
        l = -logf(p);
    }
    if (t < 64) {
        const float tot = wave_reduce(l);
        if (t == 0) out[0] = tot / ((float)n + 1e-9f);
    }
}

// ---------- fallback path (plain 2-launch), used only if cooperative launch fails ----------
__global__ __launch_bounds__(256) void pious_accum(
    const float* __restrict__ pred, const float* __restrict__ target,
    const float* __restrict__ tmpl, float* __restrict__ ws, int P) {
    const int lane = threadIdx.x & 63, wid = threadIdx.x >> 6;
    const int gw = blockIdx.x * 4 + wid;
    const float acc = task_partial(pred, target, tmpl, P,
                                   blockIdx.y, blockIdx.z, gw, lane);
    __shared__ float red[4];
    const float r = wave_reduce(acc);
    if (lane == 0) red[wid] = r;
    __syncthreads();
    if (threadIdx.x == 0)
        ws[(blockIdx.y * 3 + blockIdx.z) * CHUNKS + blockIdx.x] =
            red[0] + red[1] + red[2] + red[3];
}

__global__ __launch_bounds__(128) void pious_final(
    const float* __restrict__ ws, float* __restrict__ out, int n) {
    __shared__ float sums[128];
    const int t = threadIdx.x;
    if (t < 3 * n) {
        float s = 0.f;
#pragma unroll
        for (int c = 0; c < CHUNKS; ++c) s += ws[t * CHUNKS + c];
        sums[t] = s;
    }
    __syncthreads();
    float l = 0.f;
    if (t < n) {
        const float ap    = sums[t * 3 + 0];
        const float at    = sums[t * 3 + 1];
        const float inter = sums[t * 3 + 2];
        float p = inter / (ap + at - inter + 1e-6f);
        p = fminf(fmaxf(p, 0.1f), 1.0f);
        l = -logf(p);
    }
    if (t < 64) {
        const float tot = wave_reduce(l);
        if (t == 0) out[0] = tot / ((float)n + 1e-9f);
    }
}

extern "C" void kernel_launch(void* const* d_in, const int* in_sizes, int n_in,
                              void* d_out, int out_size, void* d_ws, size_t ws_size,
                              hipStream_t stream) {
    const float* pred   = (const float*)d_in[0];
    const float* target = (const float*)d_in[1];
    const float* tmpl   = (const float*)d_in[2];
    float* out = (float*)d_out;
    float* ws  = (float*)d_ws;

    const int n = in_sizes[0] / 5;   // 32 boxes
    const int P = in_sizes[2];       // 1224

    dim3 grid(CHUNKS, n, 3);
    void* args[] = {(void*)&pred, (void*)&target, (void*)&tmpl,
                    (void*)&ws, (void*)&out, (void*)&P, (void*)&n};
    if (hipLaunchCooperativeKernel((const void*)pious_fused, grid,
                                   dim3(256, 1, 1), args, 0, stream) != hipSuccess) {
        // cooperative launch not capturable -> plain 2-kernel path
        pious_accum<<<grid, 256, 0, stream>>>(pred, target, tmpl, ws, P);
        pious_final<<<1, 128, 0, stream>>>(ws, out, n);
    }
}

// Round 2
// 67.877 us; speedup vs baseline: 1.5853x; 1.5853x over previous
//
#include <hip/hip_runtime.h>

#define K_SOFT 10.0f
#define LOG2E  1.4426950408889634f
#define MARGIN 3.0f      // e^(-10*3) ~ 1e-13 per omitted pixel -> truncation ~1e-7 total
#define CHUNKS 4         // row-chunk blocks per task (phase-1 parallelism)

__device__ __forceinline__ float wave_reduce(float v) {
#pragma unroll
    for (int off = 32; off > 0; off >>= 1)
        v += __shfl_down(v, off, 64);
    return v;
}

struct Box {
    float cx, cy, kca, ksa, wc, hc;  // kca/ksa = k2*cos/sin; wc/hc = k2*w/2, k2*h/2
    int x0, x1, y0, y1;              // clamped template-index AABB (inclusive)
};

__device__ __forceinline__ Box make_box(const float* __restrict__ p, int i,
                                        float k2, float t0, float inv_dt, int P) {
    Box b;
    b.cx = p[i * 5 + 0];
    b.cy = p[i * 5 + 1];
    const float w = p[i * 5 + 2], h = p[i * 5 + 3], a = p[i * 5 + 4];
    const float ca = cosf(a), sa = sinf(a);
    b.kca = k2 * ca;
    b.ksa = k2 * sa;
    b.wc  = k2 * 0.5f * w;
    b.hc  = k2 * 0.5f * h;
    // AABB of the rotated (w+2M) x (h+2M) support rectangle
    const float hw = 0.5f * w + MARGIN, hh = 0.5f * h + MARGIN;
    const float aca = fabsf(ca), asa = fabsf(sa);
    const float ex = hw * aca + hh * asa;
    const float ey = hw * asa + hh * aca;
    b.x0 = max(0,     (int)ceilf ((b.cx - ex - t0) * inv_dt));
    b.x1 = min(P - 1, (int)floorf((b.cx + ex - t0) * inv_dt));
    b.y0 = max(0,     (int)ceilf ((b.cy - ey - t0) * inv_dt));
    b.y1 = min(P - 1, (int)floorf((b.cy + ey - t0) * inv_dt));
    return b;
}

// Per-block partial sum for task (box, which): 0 = area_p, 1 = area_t, 2 = inter.
// Template is an exact arithmetic progression (dt == 1.0), so pixel coordinates
// are computed by FMA instead of loads; k2 is folded into all row constants.
__device__ __forceinline__ float task_partial(
    const float* __restrict__ pred, const float* __restrict__ target,
    const float* __restrict__ tmpl, int P, int box, int which, int gw, int lane) {
    const float k2 = K_SOFT * LOG2E;
    const float t0 = tmpl[0], dt = tmpl[1] - tmpl[0];
    const float inv_dt = 1.0f / dt;
    const int wstride = 4 * CHUNKS;
    float acc = 0.f;

    if (which < 2) {
        const Box A = make_box(which == 0 ? pred : target, box, k2, t0, inv_dt, P);
        const float bx = t0 - A.cx;
        const float xT = dt * A.kca;    // dT/dxx
        const float xD = -dt * A.ksa;   // dD/dxx
        for (int yy = A.y0 + gw; yy <= A.y1; yy += wstride) {
            const float dyv = fmaf((float)yy, dt, t0) - A.cy;
            const float tb = fmaf(bx,  A.kca, dyv * A.ksa);
            const float db = fmaf(bx, -A.ksa, dyv * A.kca);
            float xf = (float)(A.x0 + lane);
            for (int xx = A.x0 + lane; xx <= A.x1; xx += 64, xf += 64.f) {
                const float T = fmaf(xf, xT, tb);
                const float D = fmaf(xf, xD, db);
                const float e1 = exp2f(fabsf(T) - A.wc);
                const float e2 = exp2f(fabsf(D) - A.hc);
                acc += __builtin_amdgcn_rcpf(1.f + e1) *
                       __builtin_amdgcn_rcpf(1.f + e2);
            }
        }
    } else {
        const Box A = make_box(pred,   box, k2, t0, inv_dt, P);
        const Box B = make_box(target, box, k2, t0, inv_dt, P);
        const int x0 = max(A.x0, B.x0), x1 = min(A.x1, B.x1);
        const int y0 = max(A.y0, B.y0), y1 = min(A.y1, B.y1);
        const float bxA = t0 - A.cx, bxB = t0 - B.cx;
        const float xTA = dt * A.kca, xDA = -dt * A.ksa;
        const float xTB = dt * B.kca, xDB = -dt * B.ksa;
        for (int yy = y0 + gw; yy <= y1; yy += wstride) {
            const float yv = fmaf((float)yy, dt, t0);
            const float dyA = yv - A.cy, dyB = yv - B.cy;
            const float tbA = fmaf(bxA,  A.kca, dyA * A.ksa);
            const float dbA = fmaf(bxA, -A.ksa, dyA * A.kca);
            const float tbB = fmaf(bxB,  B.kca, dyB * B.ksa);
            const float dbB = fmaf(bxB, -B.ksa, dyB * B.kca);
            float xf = (float)(x0 + lane);
            for (int xx = x0 + lane; xx <= x1; xx += 64, xf += 64.f) {
                const float TA = fmaf(xf, xTA, tbA);
                const float DA = fmaf(xf, xDA, dbA);
                const float eA1 = exp2f(fabsf(TA) - A.wc);
                const float eA2 = exp2f(fabsf(DA) - A.hc);
                const float kp = __builtin_amdgcn_rcpf(1.f + eA1) *
                                 __builtin_amdgcn_rcpf(1.f + eA2);
                const float TB = fmaf(xf, xTB, tbB);
                const float DB = fmaf(xf, xDB, dbB);
                const float eB1 = exp2f(fabsf(TB) - B.wc);
                const float eB2 = exp2f(fabsf(DB) - B.hc);
                const float kt = __builtin_amdgcn_rcpf(1.f + eB1) *
                                 __builtin_amdgcn_rcpf(1.f + eB2);
                acc = fmaf(kp, kt, acc);
            }
        }
    }
    return acc;
}

// Single kernel, last-block-done finalize (no grid barrier — cg sync costs ~40us
// on gfx950, measured round 1). grid = (CHUNKS, n, 3), block = 256.
// ws layout: [0] u32 counter (memset to 0 on stream before launch),
//            [64..] 3n*CHUNKS float partials (offset keeps counter on its own line).
__global__ __launch_bounds__(256) void pious_fused(
    const float* __restrict__ pred, const float* __restrict__ target,
    const float* __restrict__ tmpl, float* __restrict__ ws,
    unsigned int* __restrict__ counter, float* __restrict__ out, int P, int n) {
    const int lane = threadIdx.x & 63, wid = threadIdx.x >> 6;
    const int gw = blockIdx.x * 4 + wid;
    float* partials = ws + 64;

    const float acc = task_partial(pred, target, tmpl, P,
                                   blockIdx.y, blockIdx.z, gw, lane);

    __shared__ float red[4];
    __shared__ int is_last;
    const float r = wave_reduce(acc);
    if (lane == 0) red[wid] = r;
    __syncthreads();
    if (threadIdx.x == 0) {
        const int task = blockIdx.y * 3 + blockIdx.z;
        partials[task * CHUNKS + blockIdx.x] = red[0] + red[1] + red[2] + red[3];
        __threadfence();   // release: partial visible device-wide before the count
        const unsigned int nb = gridDim.x * gridDim.y * gridDim.z;
        is_last = (atomicAdd(counter, 1u) == nb - 1u);
    }
    __syncthreads();
    if (!is_last) return;

    // last block: every other block's release-fence + atomic happened-before our
    // observation of the final count, so partials are globally visible.
    __threadfence();   // acquire side
    __shared__ float sums[256];
    const int t = threadIdx.x;
    if (t < 3 * n) {
        float s = 0.f;
#pragma unroll
        for (int c = 0; c < CHUNKS; ++c) s += partials[t * CHUNKS + c];
        sums[t] = s;
    }
    __syncthreads();
    float l = 0.f;
    if (t < n) {   // n = 32 <= 64: all loss lanes live in wave 0
        const float ap    = sums[t * 3 + 0];
        const float at    = sums[t * 3 + 1];
        const float inter = sums[t * 3 + 2];
        float p = inter / (ap + at - inter + 1e-6f);
        p = fminf(fmaxf(p, 0.1f), 1.0f);
        l = -logf(p);
    }
    if (t < 64) {
        const float tot = wave_reduce(l);
        if (t == 0) out[0] = tot / ((float)n + 1e-9f);
    }
}

extern "C" void kernel_launch(void* const* d_in, const int* in_sizes, int n_in,
                              void* d_out, int out_size, void* d_ws, size_t ws_size,
                              hipStream_t stream) {
    const float* pred   = (const float*)d_in[0];
    const float* target = (const float*)d_in[1];
    const float* tmpl   = (const float*)d_in[2];
    float* out = (float*)d_out;
    float* ws  = (float*)d_ws;
    unsigned int* counter = (unsigned int*)d_ws;

    const int n = in_sizes[0] / 5;   // 32 boxes
    const int P = in_sizes[2];       // 1224

    // zero the arrival counter (ws is re-poisoned by the harness each iteration)
    hipMemsetAsync(counter, 0, sizeof(unsigned int), stream);

    dim3 grid(CHUNKS, n, 3);
    pious_fused<<<grid, 256, 0, stream>>>(pred, target, tmpl, ws, counter,
                                          out, P, n);
}